// Round 9
// baseline (309.202 us; speedup 1.0000x reference)
//
#include <hip/hip_runtime.h>
#include <math.h>

#define N_NODES   100000
#define N_EDGES   1600000
#define VOCAB     2048
#define NODE_DIM  64
#define HIDDEN    64
#define N_MASK    10000

#define BN        192            // nodes per bucket
#define NBKT      521            // ceil(100000/192)
#define CHUNK     2048           // edges per partition block
#define NCH       782            // ceil(N_EDGES/CHUNK)

typedef __attribute__((ext_vector_type(8))) short short8;
typedef __attribute__((ext_vector_type(4))) float f32x4;
typedef unsigned short ushort_t;
typedef unsigned int uint_t;

// ---------------- workspace layout (bytes), 16-aligned ----------------
// e2 (bucket-partitioned edges) dies after k_sortb; embW tables, W2T and X2b
// alias its region (created strictly after k_sortb on the same stream).
#define H1_OFF      0            // 100000*64 f32  = 25,600,000
#define ESRC_OFF    25600000     // 1.6M i32       =  6,400,000  (CSR order)
#define EVOC_OFF    32000000     // 1.6M i32       =  6,400,000  (CSR order)
#define E2_OFF      38400000     // 1.6M int2      = 12,800,000  (dead after sortb)
#define EWL_OFF     38400000     //   2048*64 f32  =    524,288  (aliases e2)
#define EWR_OFF     38924288     //   2048*64 f32  =    524,288
#define W2T_OFF     39448576     //   2048*128 bf16=    524,288
#define X2B_OFF     39972864     //   10000*128 bf16= 2,560,000
#define ROWPTR_OFF  51200000     // 100001 i32
#define BCNT_OFF    51600016     // 521 i32 (pad 2096)
#define BPTR_OFF    51602112     // 522 i32 (pad 2112)
#define HMAT_OFF    51604224     // 782*521 i32 = 1,629,688
// total ~53.24 MB

__device__ __forceinline__ ushort_t f2bf(float f) {
    uint_t u = __builtin_bit_cast(uint_t, f);
    u += 0x7FFFu + ((u >> 16) & 1u);        // round-to-nearest-even
    return (ushort_t)(u >> 16);
}

// one launch for all small preprocessing:
// blocks [0,512):    embWl = emb @ Wl1
// blocks [512,1024): embWr = emb @ Wr1
// blocks [1024,1088): W2T[n][k] = bf16([Wl2;Wr2]^T)
__global__ __launch_bounds__(256) void k_prep(const float* __restrict__ emb,
                                              const float* __restrict__ Wl1,
                                              const float* __restrict__ Wr1,
                                              const float* __restrict__ Wl2,
                                              const float* __restrict__ Wr2,
                                              float* __restrict__ embWl,
                                              float* __restrict__ embWr,
                                              ushort_t* __restrict__ W2T) {
    __shared__ ushort_t T[64 * 66];
    const int bx = blockIdx.x;
    const int tid = threadIdx.x;
    if (bx < 1024) {
        const int half = bx >> 9;
        const float* W = half ? Wr1 : Wl1;
        float* out = half ? embWr : embWl;
        int idx = (bx & 511) * 256 + tid;
        int v = idx >> 6, c = idx & 63;
        float s = 0.0f;
#pragma unroll 8
        for (int k = 0; k < 64; k++) s += emb[v * 64 + k] * W[k * 64 + c];
        out[idx] = s;
    } else {
        int t = bx - 1024;                    // 64 blocks: 2 k-halves x 32 n-tiles
        const int k0 = (t & 1) * 64;
        const int n0 = (t >> 1) * 64;
        const float* Wsrc = (k0 == 0) ? Wl2 : Wr2;
#pragma unroll
        for (int i = 0; i < 16; i++) {
            int idx = i * 256 + tid;
            int k = idx >> 6, n = idx & 63;
            T[n * 66 + k] = f2bf(Wsrc[(size_t)k * VOCAB + n0 + n]);
        }
        __syncthreads();
#pragma unroll
        for (int i = 0; i < 16; i++) {
            int idx = i * 256 + tid;
            int n = idx >> 6, k = idx & 63;
            W2T[(size_t)(n0 + n) * 128 + k0 + k] = T[n * 66 + k];
        }
    }
}

// per-chunk bucket histogram -> H[chunk][k]; fire-and-forget totals -> bcnt
__global__ __launch_bounds__(256) void k_hist2d(const int* __restrict__ dst,
                                                int* __restrict__ H,
                                                int* __restrict__ bcnt) {
    __shared__ int hist[NBKT];
    for (int i = threadIdx.x; i < NBKT; i += 256) hist[i] = 0;
    __syncthreads();
    const int e0 = blockIdx.x * CHUNK;
    const int n = min(CHUNK, N_EDGES - e0);
    for (int i = threadIdx.x; i < n; i += 256)
        atomicAdd(&hist[dst[e0 + i] / BN], 1);
    __syncthreads();
    for (int i = threadIdx.x; i < NBKT; i += 256) {
        int c = hist[i];
        H[blockIdx.x * NBKT + i] = c;
        if (c) atomicAdd(&bcnt[i], c);       // no return value -> no stall
    }
}

// exclusive scan of 521 bucket totals -> bptr; rowptr[N] = N_EDGES
__global__ __launch_bounds__(1024) void k_bscan(const int* __restrict__ bcnt,
                                                int* __restrict__ bptr,
                                                int* __restrict__ rowptr) {
    __shared__ int s[1024];
    int t = threadIdx.x;
    int v = (t < NBKT) ? bcnt[t] : 0;
    s[t] = v;
    __syncthreads();
    for (int off = 1; off < 1024; off <<= 1) {
        int a = (t >= off) ? s[t - off] : 0;
        __syncthreads();
        s[t] += a;
        __syncthreads();
    }
    if (t < NBKT) bptr[t] = s[t] - v;
    if (t == NBKT - 1) bptr[NBKT] = s[t];
    if (t == 0) rowptr[N_NODES] = N_EDGES;
}

// column scan: H[c][k] -> bptr[k] + prefix over chunks (exact base cursors).
// one wave per bucket, shfl-based 64-wide scan, 13 rounds.
__global__ __launch_bounds__(64) void k_cscan(const int* __restrict__ bptr,
                                              int* __restrict__ H) {
    const int k = blockIdx.x;
    const int lane = threadIdx.x;
    int run = bptr[k];
    for (int base = 0; base < NCH; base += 64) {
        int c = base + lane;
        int v = (c < NCH) ? H[c * NBKT + k] : 0;
        int incl = v;
#pragma unroll
        for (int off = 1; off < 64; off <<= 1) {
            int t = __shfl_up(incl, off);
            if (lane >= off) incl += t;
        }
        if (c < NCH) H[c * NBKT + k] = run + incl - v;
        run += __shfl(incl, 63);
    }
}

// single-pass partition: LDS cursors preloaded from H row (deterministic,
// zero global atomics). e2 = (src, voc<<8 | dst%BN), bucket-contiguous.
__global__ __launch_bounds__(256) void k_scatter2(const int* __restrict__ src,
                                                  const int* __restrict__ dst,
                                                  const int* __restrict__ x,
                                                  const int* __restrict__ H,
                                                  int2* __restrict__ e2) {
    __shared__ int cur[NBKT];
    for (int i = threadIdx.x; i < NBKT; i += 256)
        cur[i] = H[blockIdx.x * NBKT + i];
    __syncthreads();
    const int e0 = blockIdx.x * CHUNK;
    const int n = min(CHUNK, N_EDGES - e0);
    for (int i = threadIdx.x; i < n; i += 256) {
        int d = dst[e0 + i];
        int b = d / BN;                       // compile-time magic-mul
        int s = src[e0 + i];
        int voc = x[s];
        int pos = atomicAdd(&cur[b], 1);      // LDS atomic, low contention
        e2[pos] = make_int2(s, (voc << 8) | (d - b * BN));
    }
}

// per-bucket LDS counting sort: builds rowptr (coalesced) and CSR-ordered
// esrc/evoc. Scatter stays inside the bucket's own L2-resident window.
__global__ __launch_bounds__(256) void k_sortb(const int* __restrict__ bptr,
                                               const int2* __restrict__ e2,
                                               int* __restrict__ rowptr,
                                               int* __restrict__ esrc,
                                               int* __restrict__ evoc) {
    __shared__ int cnt[BN];
    __shared__ int s[256];
    __shared__ int cur[BN];
    const int b = blockIdx.x;
    const int t = threadIdx.x;
    const int r0 = bptr[b], r1 = bptr[b + 1];
    if (t < BN) cnt[t] = 0;
    __syncthreads();
    for (int e = r0 + t; e < r1; e += 256)
        atomicAdd(&cnt[e2[e].y & 255], 1);
    __syncthreads();
    int v = (t < BN) ? cnt[t] : 0;
    s[t] = v;
    __syncthreads();
    for (int off = 1; off < 256; off <<= 1) {
        int a = (t >= off) ? s[t - off] : 0;
        __syncthreads();
        s[t] += a;
        __syncthreads();
    }
    if (t < BN) {
        int excl = s[t] - v;
        cur[t] = excl;
        int node = b * BN + t;
        if (node < N_NODES) rowptr[node] = r0 + excl;
    }
    __syncthreads();
    for (int e = r0 + t; e < r1; e += 256) {
        int2 ev = e2[e];
        int pos = r0 + atomicAdd(&cur[ev.y & 255], 1);
        esrc[pos] = ev.x;
        evoc[pos] = ev.y >> 8;
    }
}

// h1[n] = relu( mean_e embWl[voc_e] + embWr[x[n]] + b1 ), one wave per node.
// Lane-parallel descriptor staging + __shfl broadcast: gathers issued 4-wide.
__global__ __launch_bounds__(256) void k_agg1(const int* __restrict__ rowptr,
                                              const int* __restrict__ evoc,
                                              const int* __restrict__ x,
                                              const float* __restrict__ embWl,
                                              const float* __restrict__ embWr,
                                              const float* __restrict__ b1,
                                              float* __restrict__ h1) {
    int gw = (blockIdx.x * 256 + threadIdx.x) >> 6;
    int lane = threadIdx.x & 63;
    if (gw >= N_NODES) return;
    int r0 = rowptr[gw], r1 = rowptr[gw + 1];
    int deg = r1 - r0;
    float s0 = 0.0f, s1 = 0.0f, s2 = 0.0f, s3 = 0.0f;
    for (int base = 0; base < deg; base += 64) {
        int cnt = min(64, deg - base);
        int myv = (base + lane < deg) ? evoc[r0 + base + lane] : 0;
        int t = 0;
        for (; t + 3 < cnt; t += 4) {
            int va = __shfl(myv, t);
            int vb = __shfl(myv, t + 1);
            int vc = __shfl(myv, t + 2);
            int vd = __shfl(myv, t + 3);
            s0 += embWl[(va << 6) + lane];
            s1 += embWl[(vb << 6) + lane];
            s2 += embWl[(vc << 6) + lane];
            s3 += embWl[(vd << 6) + lane];
        }
        for (; t < cnt; t++)
            s0 += embWl[(__shfl(myv, t) << 6) + lane];
    }
    float sum = (s0 + s1) + (s2 + s3);
    float inv = 1.0f / fmaxf((float)deg, 1.0f);
    float self = embWr[(x[gw] << 6) + lane];
    h1[((size_t)gw << 6) + lane] = fmaxf(sum * inv + self + b1[lane], 0.0f);
}

// X2b[m] = bf16[ mean_e h1[src_e] | h1[mask[m]] ], one wave per masked row
__global__ __launch_bounds__(256) void k_x2(const int* __restrict__ mask,
                                            const int* __restrict__ rowptr,
                                            const int* __restrict__ esrc,
                                            const float* __restrict__ h1,
                                            ushort_t* __restrict__ X2b) {
    int gw = (blockIdx.x * 256 + threadIdx.x) >> 6;
    int lane = threadIdx.x & 63;
    if (gw >= N_MASK) return;
    int n = mask[gw];
    int r0 = rowptr[n], r1 = rowptr[n + 1];
    int deg = r1 - r0;
    float s0 = 0.0f, s1 = 0.0f, s2 = 0.0f, s3 = 0.0f;
    for (int base = 0; base < deg; base += 64) {
        int cnt = min(64, deg - base);
        int mys = (base + lane < deg) ? esrc[r0 + base + lane] : 0;
        int t = 0;
        for (; t + 3 < cnt; t += 4) {
            int sa = __shfl(mys, t);
            int sb = __shfl(mys, t + 1);
            int sc = __shfl(mys, t + 2);
            int sd = __shfl(mys, t + 3);
            s0 += h1[((size_t)sa << 6) + lane];
            s1 += h1[((size_t)sb << 6) + lane];
            s2 += h1[((size_t)sc << 6) + lane];
            s3 += h1[((size_t)sd << 6) + lane];
        }
        for (; t < cnt; t++)
            s0 += h1[((size_t)__shfl(mys, t) << 6) + lane];
    }
    float sum = (s0 + s1) + (s2 + s3);
    float inv = 1.0f / fmaxf((float)deg, 1.0f);
    X2b[gw * 128 + lane]      = f2bf(sum * inv);
    X2b[gw * 128 + 64 + lane] = f2bf(h1[((size_t)n << 6) + lane]);
}

// Fused GEMM + log_softmax. One block = 16 rows x 2048 cols.
// Wave w covers cols {c*64 + w*16 + (lane&15)} for c in [0,32); acc[c] is the
// 16x16 MFMA tile (C layout: col=lane&15, row=(lane>>4)*4+reg). A-frags live
// in registers (same 16 rows for all waves); B-frags stream from L2-resident
// W2T. Row max/sum: quad shfl-reduce + 4-wave LDS combine. out written once.
__global__ __launch_bounds__(256) void k_gemm2ls(const ushort_t* __restrict__ X2b,
                                                 const ushort_t* __restrict__ W2T,
                                                 const float* __restrict__ bias,
                                                 float* __restrict__ out) {
    const int tid  = threadIdx.x;
    const int lane = tid & 63;
    const int w    = tid >> 6;
    const int l15  = lane & 15, q = lane >> 4;
    const int row0 = blockIdx.x * 16;

    const ushort_t* Arow = X2b + (size_t)(row0 + l15) * 128 + q * 8;
    short8 a[4];
#pragma unroll
    for (int ks = 0; ks < 4; ks++) a[ks] = *(const short8*)(Arow + ks * 32);

    f32x4 acc[32];
#pragma unroll
    for (int c = 0; c < 32; c++) {
        const int colbase = c * 64 + w * 16;
        float bv = bias[colbase + l15];
        acc[c] = (f32x4){bv, bv, bv, bv};
        const ushort_t* Brow = W2T + (size_t)(colbase + l15) * 128 + q * 8;
#pragma unroll
        for (int ks = 0; ks < 4; ks++) {
            short8 b = *(const short8*)(Brow + ks * 32);
            acc[c] = __builtin_amdgcn_mfma_f32_16x16x32_bf16(a[ks], b, acc[c], 0, 0, 0);
        }
    }

    // ---- row max ----
    float rmax[4] = {-INFINITY, -INFINITY, -INFINITY, -INFINITY};
#pragma unroll
    for (int c = 0; c < 32; c++)
#pragma unroll
        for (int r = 0; r < 4; r++) rmax[r] = fmaxf(rmax[r], acc[c][r]);
#pragma unroll
    for (int off = 1; off < 16; off <<= 1)
#pragma unroll
        for (int r = 0; r < 4; r++) rmax[r] = fmaxf(rmax[r], __shfl_xor(rmax[r], off));
    __shared__ float smax[4][16];
    __shared__ float ssum[4][16];
    if (l15 == 0)
#pragma unroll
        for (int r = 0; r < 4; r++) smax[w][q * 4 + r] = rmax[r];
    __syncthreads();
#pragma unroll
    for (int r = 0; r < 4; r++) {
        int row = q * 4 + r;
        rmax[r] = fmaxf(fmaxf(smax[0][row], smax[1][row]),
                        fmaxf(smax[2][row], smax[3][row]));
    }
    // ---- row sum of exp ----
    float rsum[4] = {0.0f, 0.0f, 0.0f, 0.0f};
#pragma unroll
    for (int c = 0; c < 32; c++)
#pragma unroll
        for (int r = 0; r < 4; r++) rsum[r] += __expf(acc[c][r] - rmax[r]);
#pragma unroll
    for (int off = 1; off < 16; off <<= 1)
#pragma unroll
        for (int r = 0; r < 4; r++) rsum[r] += __shfl_xor(rsum[r], off);
    if (l15 == 0)
#pragma unroll
        for (int r = 0; r < 4; r++) ssum[w][q * 4 + r] = rsum[r];
    __syncthreads();
    float L[4];
#pragma unroll
    for (int r = 0; r < 4; r++) {
        int row = q * 4 + r;
        L[r] = rmax[r] + __logf(ssum[0][row] + ssum[1][row] +
                                ssum[2][row] + ssum[3][row]);
    }
    // ---- write log-softmax directly ----
#pragma unroll
    for (int c = 0; c < 32; c++) {
        int col = c * 64 + w * 16 + l15;
#pragma unroll
        for (int r = 0; r < 4; r++)
            out[(size_t)(row0 + q * 4 + r) * VOCAB + col] = acc[c][r] - L[r];
    }
}

extern "C" void kernel_launch(void* const* d_in, const int* in_sizes, int n_in,
                              void* d_out, int out_size, void* d_ws, size_t ws_size,
                              hipStream_t stream) {
    const int*   x    = (const int*)d_in[0];
    const int*   ei   = (const int*)d_in[1];
    const int*   src  = ei;
    const int*   dst  = ei + N_EDGES;
    const int*   mask = (const int*)d_in[2];
    const float* emb  = (const float*)d_in[3];
    const float* Wl1  = (const float*)d_in[4];
    const float* bl1  = (const float*)d_in[5];
    const float* Wr1  = (const float*)d_in[6];
    const float* Wl2  = (const float*)d_in[7];
    const float* bl2  = (const float*)d_in[8];
    const float* Wr2  = (const float*)d_in[9];
    float* out = (float*)d_out;

    char* ws = (char*)d_ws;
    float*    h1     = (float*)(ws + H1_OFF);
    int*      esrc   = (int*)(ws + ESRC_OFF);
    int*      evoc   = (int*)(ws + EVOC_OFF);
    int2*     e2     = (int2*)(ws + E2_OFF);
    float*    embWl  = (float*)(ws + EWL_OFF);     // aliases e2 (after sortb)
    float*    embWr  = (float*)(ws + EWR_OFF);
    ushort_t* W2T    = (ushort_t*)(ws + W2T_OFF);
    ushort_t* X2b    = (ushort_t*)(ws + X2B_OFF);
    int*      rowptr = (int*)(ws + ROWPTR_OFF);
    int*      bcnt   = (int*)(ws + BCNT_OFF);
    int*      bptr   = (int*)(ws + BPTR_OFF);
    int*      Hm     = (int*)(ws + HMAT_OFF);

    hipMemsetAsync(ws + BCNT_OFF, 0, 2096, stream);          // bucket totals = 0

    // ---- CSR build: deterministic 2D-histogram partition + bucket sort ----
    k_hist2d  <<<NCH, 256, 0, stream>>>(dst, Hm, bcnt);
    k_bscan   <<<1, 1024, 0, stream>>>(bcnt, bptr, rowptr);
    k_cscan   <<<NBKT, 64, 0, stream>>>(bptr, Hm);
    k_scatter2<<<NCH, 256, 0, stream>>>(src, dst, x, Hm, e2);
    k_sortb   <<<NBKT, 256, 0, stream>>>(bptr, e2, rowptr, esrc, evoc);

    // ---- small transformed tables (placed in e2's dead region) ----
    k_prep<<<1088, 256, 0, stream>>>(emb, Wl1, Wr1, Wl2, Wr2, embWl, embWr, W2T);

    // ---- layer 1: node-parallel CSR aggregation, fused epilogue ----
    k_agg1<<<(N_NODES * 64 + 255) / 256, 256, 0, stream>>>(rowptr, evoc, x, embWl, embWr, bl1, h1);

    // ---- layer 2: masked-row gather -> bf16 X2, fused MFMA GEMM + softmax ----
    k_x2<<<(N_MASK * 64 + 255) / 256, 256, 0, stream>>>(mask, rowptr, esrc, h1, X2b);
    k_gemm2ls<<<N_MASK / 16, 256, 0, stream>>>(X2b, W2T, bl2, out);
}